// Round 19
// baseline (110.996 us; speedup 1.0000x reference)
//
#include <hip/hip_runtime.h>
#include <hip/hip_bf16.h>
#include <math.h>

#define HNUM 16
#define DH 64
#define NSEQ 1024
#define BATCH 2
#define DMODEL 1024
#define SCALE 0.125f
#define EPS 1e-6f
#define NUM_ITER 4
#define SPAD_T 1080  // u16/row: 2160B = 135 16B-slots (odd) -> frag reads 2-way max (free)

typedef float f32x4 __attribute__((ext_vector_type(4)));
typedef short bfrag __attribute__((ext_vector_type(8)));     // 8 bf16 = 4 VGPR
typedef unsigned int u32x4 __attribute__((ext_vector_type(4)));

__device__ inline float bf2f_u(unsigned int u) {
    return __builtin_bit_cast(float, u << 16);
}
__device__ inline unsigned short f2bf_u(float f) {
    return __builtin_bit_cast(unsigned short, __float2bfloat16(f));
}
__device__ inline ushort4 cvt4(const float4 v) {
    ushort4 o;
    o.x = f2bf_u(v.x); o.y = f2bf_u(v.y); o.z = f2bf_u(v.z); o.w = f2bf_u(v.w);
    return o;
}

// async global->LDS, 16B per lane; LDS dest must be lane-linear (it is).
__device__ inline void gload16(const __hip_bfloat16* g, __hip_bfloat16* l) {
    __builtin_amdgcn_global_load_lds(
        (const __attribute__((address_space(1))) void*)g,
        (__attribute__((address_space(3))) void*)l, 16, 0, 0);
}

// ---------------------------------------------------------------------------
// DPP wave64 reductions (R16, proven): VALU-pipe latency instead of DS-pipe.
// SUM: bound_ctrl fetch-0 (invalid lanes add +0.0, exact).
// MAX: old = own value (fmax(x,x), exact).
// ---------------------------------------------------------------------------
__device__ __forceinline__ float dpp_sum64(float x) {
    int v = __builtin_bit_cast(int, x);
    float t;
    t = __builtin_bit_cast(float, __builtin_amdgcn_update_dpp(0, v, 0x111, 0xf, 0xf, true));  x += t; v = __builtin_bit_cast(int, x);
    t = __builtin_bit_cast(float, __builtin_amdgcn_update_dpp(0, v, 0x112, 0xf, 0xf, true));  x += t; v = __builtin_bit_cast(int, x);
    t = __builtin_bit_cast(float, __builtin_amdgcn_update_dpp(0, v, 0x114, 0xf, 0xf, true));  x += t; v = __builtin_bit_cast(int, x);
    t = __builtin_bit_cast(float, __builtin_amdgcn_update_dpp(0, v, 0x118, 0xf, 0xf, true));  x += t; v = __builtin_bit_cast(int, x);
    t = __builtin_bit_cast(float, __builtin_amdgcn_update_dpp(0, v, 0x142, 0xf, 0xf, true));  x += t; v = __builtin_bit_cast(int, x);
    t = __builtin_bit_cast(float, __builtin_amdgcn_update_dpp(0, v, 0x143, 0xf, 0xf, true));  x += t; v = __builtin_bit_cast(int, x);
    return __builtin_bit_cast(float, __builtin_amdgcn_readlane(v, 63));
}
__device__ __forceinline__ float dpp_max64(float x) {
    int v = __builtin_bit_cast(int, x);
    float t;
    t = __builtin_bit_cast(float, __builtin_amdgcn_update_dpp(v, v, 0x111, 0xf, 0xf, false)); x = fmaxf(x, t); v = __builtin_bit_cast(int, x);
    t = __builtin_bit_cast(float, __builtin_amdgcn_update_dpp(v, v, 0x112, 0xf, 0xf, false)); x = fmaxf(x, t); v = __builtin_bit_cast(int, x);
    t = __builtin_bit_cast(float, __builtin_amdgcn_update_dpp(v, v, 0x114, 0xf, 0xf, false)); x = fmaxf(x, t); v = __builtin_bit_cast(int, x);
    t = __builtin_bit_cast(float, __builtin_amdgcn_update_dpp(v, v, 0x118, 0xf, 0xf, false)); x = fmaxf(x, t); v = __builtin_bit_cast(int, x);
    t = __builtin_bit_cast(float, __builtin_amdgcn_update_dpp(v, v, 0x142, 0xf, 0xf, false)); x = fmaxf(x, t); v = __builtin_bit_cast(int, x);
    t = __builtin_bit_cast(float, __builtin_amdgcn_update_dpp(v, v, 0x143, 0xf, 0xf, false)); x = fmaxf(x, t); v = __builtin_bit_cast(int, x);
    return __builtin_bit_cast(float, __builtin_amdgcn_readlane(v, 63));
}

// ---------------------------------------------------------------------------
// Fused fp32 -> bf16 cast of the TWO weight tensors (x is converted inside
// gemm1's A-staging now), float4-vectorized.
// ---------------------------------------------------------------------------
__global__ __launch_bounds__(256) void cast2(const float* __restrict__ s1, __hip_bfloat16* __restrict__ d1, int n1,
                                             const float* __restrict__ s2, __hip_bfloat16* __restrict__ d2, int n2) {
    const int stride = gridDim.x * blockDim.x;
    const int tot = n1 + n2;                // in float4 units
    for (int i = blockIdx.x * blockDim.x + threadIdx.x; i < tot; i += stride) {
        const float* s; __hip_bfloat16* d; int off;
        if (i < n1) { s = s1; d = d1; off = i; }
        else        { s = s2; d = d2; off = i - n1; }
        const float4 v = *reinterpret_cast<const float4*>(&s[(size_t)off * 4]);
        *reinterpret_cast<ushort4*>(&d[(size_t)off * 4]) = cvt4(v);
    }
}

// ---------------------------------------------------------------------------
// GEMM1 (QKV projection): A = x (fp32, converted in-staging), B = Wqkv (bf16,
// global_load_lds).  FUSED V-TRANSPOSE + FUSED SCALE on Q columns.
// 64x128 tile, BK=64, 4 waves each 32x64 (2x4 frags of mfma 16x16x32).
// ---------------------------------------------------------------------------
__global__ __launch_bounds__(256) void gemm1_qkv(const float* __restrict__ A,
                                                 const __hip_bfloat16* __restrict__ B,
                                                 __hip_bfloat16* __restrict__ qkvb,
                                                 __hip_bfloat16* __restrict__ Vt,
                                                 int M, int Nc, int K) {
    __shared__ __align__(16) __hip_bfloat16 As[64 * 64];
    __shared__ __align__(16) __hip_bfloat16 Bs[128 * 64];
    const int tid  = threadIdx.x;
    const int l    = tid & 63;
    const int wave = tid >> 6;
    const int m0 = blockIdx.y * 64, n0 = blockIdx.x * 128;
    const int wr = (wave >> 1) * 32, wc = (wave & 1) * 64;
    const int lr = l & 15;
    const int lk = (l >> 4) * 8;

    f32x4 acc[2][4];
#pragma unroll
    for (int m = 0; m < 2; ++m)
#pragma unroll
        for (int n = 0; n < 4; ++n) acc[m][n] = (f32x4){0.f, 0.f, 0.f, 0.f};

    for (int k0 = 0; k0 < K; k0 += 64) {
        // B first: async global->LDS stays in flight under A's reg-staging.
#pragma unroll
        for (int p = 0; p < 4; ++p) {
            const int idx = tid + p * 256;
            const int r = idx >> 3, ce = (idx & 7) * 8;
            gload16(&B[(size_t)(n0 + r) * K + k0 + ce], &Bs[idx * 8]);
        }
        // A: 64x64 fp32 = 1024 float4-chunks, 4/thread; cvt in-register.
        float4 la[4];
#pragma unroll
        for (int p = 0; p < 4; ++p) {
            const int idx = tid + p * 256;
            const int r = idx >> 4, c4 = (idx & 15) * 4;
            la[p] = *reinterpret_cast<const float4*>(&A[(size_t)(m0 + r) * K + k0 + c4]);
        }
#pragma unroll
        for (int p = 0; p < 4; ++p) {
            const int idx = tid + p * 256;
            *reinterpret_cast<ushort4*>(&As[(idx >> 4) * 64 + (idx & 15) * 4]) = cvt4(la[p]);
        }
        __syncthreads();

#pragma unroll
        for (int kk = 0; kk < 64; kk += 32) {
            bfrag af[2], bfr[4];
#pragma unroll
            for (int m = 0; m < 2; ++m)
                af[m] = *reinterpret_cast<const bfrag*>(&As[(wr + m * 16 + lr) * 64 + kk + lk]);
#pragma unroll
            for (int n = 0; n < 4; ++n)
                bfr[n] = *reinterpret_cast<const bfrag*>(&Bs[(wc + n * 16 + lr) * 64 + kk + lk]);
#pragma unroll
            for (int m = 0; m < 2; ++m)
#pragma unroll
                for (int n = 0; n < 4; ++n)
                    acc[m][n] = __builtin_amdgcn_mfma_f32_16x16x32_bf16(
                        af[m], bfr[n], acc[m][n], 0, 0, 0);
        }
        __syncthreads();
    }

#pragma unroll
    for (int m = 0; m < 2; ++m) {
        const int row0 = m0 + wr + m * 16 + (l >> 4) * 4;   // 4-aligned, same batch
#pragma unroll
        for (int n = 0; n < 4; ++n) {
            const int col = n0 + wc + n * 16 + lr;
            if (col < 1024) {                                // Q -> qkvb, pre-scaled
#pragma unroll
                for (int j = 0; j < 4; ++j)
                    qkvb[(size_t)(row0 + j) * Nc + col] = __float2bfloat16(acc[m][n][j] * SCALE);
            } else if (col < 2048) {                         // K -> qkvb
#pragma unroll
                for (int j = 0; j < 4; ++j)
                    qkvb[(size_t)(row0 + j) * Nc + col] = __float2bfloat16(acc[m][n][j]);
            } else {                                         // V -> Vt (transposed)
                const int rc = col - 2048;
                const int bh = (row0 >> 10) * 16 + (rc >> 6);
                const int d  = rc & 63;
                ushort4 pk;
                pk.x = f2bf_u(acc[m][n][0]);
                pk.y = f2bf_u(acc[m][n][1]);
                pk.z = f2bf_u(acc[m][n][2]);
                pk.w = f2bf_u(acc[m][n][3]);
                *reinterpret_cast<ushort4*>(
                    &Vt[((size_t)(bh * 64 + d)) * 1024 + (row0 & 1023)]) = pk;
            }
        }
    }
}

// ---------------------------------------------------------------------------
// GEMM2: C[M,Nc](f32) = A[M,K](bf16) @ B[Nc,K](bf16)^T.  64x64 tile, BK=64,
// global_load_lds staging, 4 waves each 32x32 (2x2 frags).  512 blocks.
// ---------------------------------------------------------------------------
__global__ __launch_bounds__(256) void gemm_bt64(const __hip_bfloat16* __restrict__ A,
                                                 const __hip_bfloat16* __restrict__ B,
                                                 float* __restrict__ C,
                                                 int M, int Nc, int K) {
    __shared__ __align__(16) __hip_bfloat16 As[64 * 64];
    __shared__ __align__(16) __hip_bfloat16 Bs[64 * 64];
    const int tid  = threadIdx.x;
    const int l    = tid & 63;
    const int wave = tid >> 6;
    const int m0 = blockIdx.y * 64, n0 = blockIdx.x * 64;
    const int wr = (wave >> 1) * 32, wc = (wave & 1) * 32;
    const int lr = l & 15;
    const int lk = (l >> 4) * 8;

    f32x4 acc[2][2];
#pragma unroll
    for (int m = 0; m < 2; ++m)
#pragma unroll
        for (int n = 0; n < 2; ++n) acc[m][n] = (f32x4){0.f, 0.f, 0.f, 0.f};

    for (int k0 = 0; k0 < K; k0 += 64) {
#pragma unroll
        for (int p = 0; p < 2; ++p) {
            const int idx = tid + p * 256;
            const int r = idx >> 3, ce = (idx & 7) * 8;
            gload16(&A[(size_t)(m0 + r) * K + k0 + ce], &As[idx * 8]);
        }
#pragma unroll
        for (int p = 0; p < 2; ++p) {
            const int idx = tid + p * 256;
            const int r = idx >> 3, ce = (idx & 7) * 8;
            gload16(&B[(size_t)(n0 + r) * K + k0 + ce], &Bs[idx * 8]);
        }
        __syncthreads();

#pragma unroll
        for (int kk = 0; kk < 64; kk += 32) {
            bfrag af[2], bfr[2];
#pragma unroll
            for (int m = 0; m < 2; ++m)
                af[m] = *reinterpret_cast<const bfrag*>(&As[(wr + m * 16 + lr) * 64 + kk + lk]);
#pragma unroll
            for (int n = 0; n < 2; ++n)
                bfr[n] = *reinterpret_cast<const bfrag*>(&Bs[(wc + n * 16 + lr) * 64 + kk + lk]);
#pragma unroll
            for (int m = 0; m < 2; ++m)
#pragma unroll
                for (int n = 0; n < 2; ++n)
                    acc[m][n] = __builtin_amdgcn_mfma_f32_16x16x32_bf16(
                        af[m], bfr[n], acc[m][n], 0, 0, 0);
        }
        __syncthreads();
    }

#pragma unroll
    for (int m = 0; m < 2; ++m) {
        const int row0 = m0 + wr + m * 16 + (l >> 4) * 4;
#pragma unroll
        for (int n = 0; n < 2; ++n) {
            const int col = n0 + wc + n * 16 + lr;
#pragma unroll
            for (int j = 0; j < 4; ++j)
                C[(size_t)(row0 + j) * Nc + col] = acc[m][n][j];
        }
    }
}

// ---------------------------------------------------------------------------
// Dual-row Newton + fused P write-back, EXACT 128-col chunk counts,
// DPP reductions (R16, best-measured form).
// ---------------------------------------------------------------------------
template <int NCA, int NCB>
__device__ inline void newton2_wb(unsigned short* __restrict__ SA,
                                  unsigned short* __restrict__ SB,
                                  int ncolsA, int ncolsB,
                                  int limitA, int limitB, int lane) {
    float svA[NCA * 2], svB[NCB * 2];
#pragma unroll
    for (int t = 0; t < NCA; ++t) {
        const int c = lane * 2 + t * 128;
        int ca = c;
        if (t == NCA - 1) ca = (c < ncolsA) ? c : 0;   // in-region addr
        const unsigned int u = *reinterpret_cast<const unsigned int*>(&SA[ca]);
        float v0 = bf2f_u(u & 0xffffu), v1 = bf2f_u(u >> 16);
        if (t == NCA - 1) {
            v0 = (c     < ncolsA) ? v0 : -1e30f;
            v1 = (c + 1 < ncolsA) ? v1 : -1e30f;
        }
        svA[2 * t] = v0; svA[2 * t + 1] = v1;
    }
#pragma unroll
    for (int t = 0; t < NCB; ++t) {
        const int c = lane * 2 + t * 128;
        int cbm = c;
        if (t == NCB - 1) cbm = (c < ncolsB) ? c : 0;
        const unsigned int u = *reinterpret_cast<const unsigned int*>(&SB[cbm]);
        float v0 = bf2f_u(u & 0xffffu), v1 = bf2f_u(u >> 16);
        if (t == NCB - 1) {
            v0 = (c     < ncolsB) ? v0 : -1e30f;
            v1 = (c + 1 < ncolsB) ? v1 : -1e30f;
        }
        svB[2 * t] = v0; svB[2 * t + 1] = v1;
    }

    float mA = svA[0], mB = svB[0];
#pragma unroll
    for (int e = 1; e < 2 * NCA; ++e) mA = fmaxf(mA, svA[e]);
#pragma unroll
    for (int e = 1; e < 2 * NCB; ++e) mB = fmaxf(mB, svB[e]);
    mA = dpp_max64(mA);
    mB = dpp_max64(mB);
    float lamA = mA + 1.0f, lamB = mB + 1.0f;

    for (int it = 0; it < NUM_ITER; ++it) {
        float fA = 0.f, fpA = 0.f, fB = 0.f, fpB = 0.f;
#pragma unroll
        for (int e = 0; e < 2 * NCA; ++e) {
            const float iA = __builtin_amdgcn_rcpf(fmaxf(lamA - svA[e], EPS));
            fA += iA; fpA = fmaf(iA, iA, fpA);
        }
#pragma unroll
        for (int e = 0; e < 2 * NCB; ++e) {
            const float iB = __builtin_amdgcn_rcpf(fmaxf(lamB - svB[e], EPS));
            fB += iB; fpB = fmaf(iB, iB, fpB);
        }
        fA = dpp_sum64(fA);  fpA = dpp_sum64(fpA);
        fB = dpp_sum64(fB);  fpB = dpp_sum64(fpB);
        lamA += (fA - 1.0f) * __builtin_amdgcn_rcpf(fpA);
        lamB += (fB - 1.0f) * __builtin_amdgcn_rcpf(fpB);
    }

    float swA = 0.f, swB = 0.f;
#pragma unroll
    for (int e = 0; e < 2 * NCA; ++e) {
        svA[e] = __builtin_amdgcn_rcpf(fmaxf(lamA - svA[e], EPS)); swA += svA[e];
    }
#pragma unroll
    for (int e = 0; e < 2 * NCB; ++e) {
        svB[e] = __builtin_amdgcn_rcpf(fmaxf(lamB - svB[e], EPS)); swB += svB[e];
    }
    swA = dpp_sum64(swA);
    swB = dpp_sum64(swB);
    const float iswA = __builtin_amdgcn_rcpf(swA);
    const float iswB = __builtin_amdgcn_rcpf(swB);

#pragma unroll
    for (int t = 0; t < NCA; ++t) {
        const int c = lane * 2 + t * 128;
        if (t * 128 < limitA && c < limitA) {
            const unsigned int pk = (unsigned)f2bf_u(svA[2 * t] * iswA)
                                  | ((unsigned)f2bf_u(svA[2 * t + 1] * iswA) << 16);
            *reinterpret_cast<unsigned int*>(&SA[c]) = pk;
        }
    }
#pragma unroll
    for (int t = 0; t < NCB; ++t) {
        const int c = lane * 2 + t * 128;
        if (t * 128 < limitB && c < limitB) {
            const unsigned int pk = (unsigned)f2bf_u(svB[2 * t] * iswB)
                                  | ((unsigned)f2bf_u(svB[2 * t + 1] * iswB) << 16);
            *reinterpret_cast<unsigned int*>(&SB[c]) = pk;
        }
    }
}

// ---------------------------------------------------------------------------
// MFMA Stieltjes attention, PAIRED TILES + XCD swizzle + P1 prefetch + DPP
// Newton (R16 best-measured form; Q pre-scaled by gemm1 so P1 stores are
// pure pack).  1024 blocks, 512 thr / 8 waves.
// ---------------------------------------------------------------------------
__global__ __launch_bounds__(512) void attn_mfma(const __hip_bfloat16* __restrict__ qkvb,
                                                 const __hip_bfloat16* __restrict__ Vt,
                                                 __hip_bfloat16* __restrict__ obf) {
    const int tid  = threadIdx.x;
    const int lane = tid & 63;
    const int wave = tid >> 6;               // 0..7
    const int bid  = ((blockIdx.x & 7) << 7) | (blockIdx.x >> 3);   // XCD swizzle
    const int pair = bid & 31;
    const int bh   = bid >> 5;
    const int b = bh >> 4, h = bh & 15;
    const int qtA = pair, qtB = 63 - pair;
    const int r0A = qtA * 16, r0B = qtB * 16;
    const int sbBase = r0A + 32;             // 16-elem multiple -> 32B aligned

    __shared__ __align__(16) unsigned short S[16][SPAD_T];

    const size_t qbase = (size_t)(b * NSEQ) * 3072;
    const int lr  = lane & 15;
    const int lk8 = (lane >> 4) * 8;
    const int rj0 = (lane >> 4) * 4;

    // ---- Q fragments for both tiles (pre-scaled by gemm1) ----
    const __hip_bfloat16* qrowA = qkvb + qbase + (size_t)(r0A + lr) * 3072 + h * 64;
    const __hip_bfloat16* qrowB = qkvb + qbase + (size_t)(r0B + lr) * 3072 + h * 64;
    const bfrag aA0 = *reinterpret_cast<const bfrag*>(&qrowA[lk8]);
    const bfrag aA1 = *reinterpret_cast<const bfrag*>(&qrowA[32 + lk8]);
    const bfrag aB0 = *reinterpret_cast<const bfrag*>(&qrowB[lk8]);
    const bfrag aB1 = *reinterpret_cast<const bfrag*>(&qrowB[32 + lk8]);
    const __hip_bfloat16* kglob = qkvb + qbase + 1024 + h * 64;

    // ---- zero strips [r0+16, r0+32) of each tile: waves 0 and 1 ----
    if (wave < 2) {
        const int cb  = wave ? sbBase : 0;
        const int qtX = wave ? qtB : qtA;
        const int cs  = cb + (qtX + 1) * 16 + lr;
#pragma unroll
        for (int j = 0; j < 4; ++j)
            S[rj0 + j][cs] = 0;
    }

    // ---- phase 1: QK^T (pre-scaled Q), depth-1 prefetch ----
    {
        const int ntA1 = qtA + 1;
        const int ntot = ntA1 + qtB + 1;
        int t = wave;
        bool isA = true; int jt = 0;
        bfrag b0{}, b1{};
        if (t < ntot) {
            isA = (t < ntA1);
            jt  = isA ? t : t - ntA1;
            const __hip_bfloat16* kp = &kglob[(size_t)(jt * 16 + lr) * 3072];
            b0 = *reinterpret_cast<const bfrag*>(&kp[lk8]);
            b1 = *reinterpret_cast<const bfrag*>(&kp[32 + lk8]);
        }
        while (t < ntot) {
            const int t2 = t + 8;
            bool isA2 = false; int jt2 = 0;
            bfrag nb0{}, nb1{};
            if (t2 < ntot) {                          // prefetch next task's K
                isA2 = (t2 < ntA1);
                jt2  = isA2 ? t2 : t2 - ntA1;
                const __hip_bfloat16* kp2 = &kglob[(size_t)(jt2 * 16 + lr) * 3072];
                nb0 = *reinterpret_cast<const bfrag*>(&kp2[lk8]);
                nb1 = *reinterpret_cast<const bfrag*>(&kp2[32 + lk8]);
            }
            f32x4 c = (f32x4){0.f, 0.f, 0.f, 0.f};
            c = __builtin_amdgcn_mfma_f32_16x16x32_bf16(isA ? aA0 : aB0, b0, c, 0, 0, 0);
            c = __builtin_amdgcn_mfma_f32_16x16x32_bf16(isA ? aA1 : aB1, b1, c, 0, 0, 0);
            const int cb = isA ? 0 : sbBase;
#pragma unroll
            for (int j = 0; j < 4; ++j)
                S[rj0 + j][cb + jt * 16 + lr] = f2bf_u(c[j]);
            t = t2; isA = isA2; jt = jt2; b0 = nb0; b1 = nb1;
        }
    }
    __syncthreads();

    // ---- phase 2: paired-row Newton w/ fused write-back, exact chunks ----
    {
        const int limitA = r0A + 16, limitB = r0B + 16;
        for (int p = 0; p < 2; ++p) {
            const int row = wave * 2 + p;
            const int ncolsA = r0A + row + 1, ncolsB = r0B + row + 1;
            const int nca = (ncolsA + 127) >> 7;      // 1..4
            const int ncb = (ncolsB + 127) >> 7;      // 5..8
            switch ((nca - 1) * 4 + (ncb - 5)) {
                case 0:  newton2_wb<1, 5>(&S[row][0], &S[row][sbBase], ncolsA, ncolsB, limitA, limitB, lane); break;
                case 1:  newton2_wb<1, 6>(&S[row][0], &S[row][sbBase], ncolsA, ncolsB, limitA, limitB, lane); break;
                case 2:  newton2_wb<1, 7>(&S[row][0], &S[row][sbBase], ncolsA, ncolsB, limitA, limitB, lane); break;
                case 3:  newton2_wb<1, 8>(&S[row][0], &S[row][sbBase], ncolsA, ncolsB, limitA, limitB, lane); break;
                case 4:  newton2_wb<2, 5>(&S[row][0], &S[row][sbBase], ncolsA, ncolsB, limitA, limitB, lane); break;
                case 5:  newton2_wb<2, 6>(&S[row][0], &S[row][sbBase], ncolsA, ncolsB, limitA, limitB, lane); break;
                case 6:  newton2_wb<2, 7>(&S[row][0], &S[row][sbBase], ncolsA, ncolsB, limitA, limitB, lane); break;
                case 7:  newton2_wb<2, 8>(&S[row][0], &S[row][sbBase], ncolsA, ncolsB, limitA, limitB, lane); break;
                case 8:  newton2_wb<3, 5>(&S[row][0], &S[row][sbBase], ncolsA, ncolsB, limitA, limitB, lane); break;
                case 9:  newton2_wb<3, 6>(&S[row][0], &S[row][sbBase], ncolsA, ncolsB, limitA, limitB, lane); break;
                case 10: newton2_wb<3, 7>(&S[row][0], &S[row][sbBase], ncolsA, ncolsB, limitA, limitB, lane); break;
                case 11: newton2_wb<3, 8>(&S[row][0], &S[row][sbBase], ncolsA, ncolsB, limitA, limitB, lane); break;
                case 12: newton2_wb<4, 5>(&S[row][0], &S[row][sbBase], ncolsA, ncolsB, limitA, limitB, lane); break;
                case 13: newton2_wb<4, 6>(&S[row][0], &S[row][sbBase], ncolsA, ncolsB, limitA, limitB, lane); break;
                case 14: newton2_wb<4, 7>(&S[row][0], &S[row][sbBase], ncolsA, ncolsB, limitA, limitB, lane); break;
                default: newton2_wb<4, 8>(&S[row][0], &S[row][sbBase], ncolsA, ncolsB, limitA, limitB, lane); break;
            }
        }
    }
    __syncthreads();

    // ---- phase 3: O = P.V; waves 0-3 -> tile A, 4-7 -> tile B ----
    {
        const int tile = wave >> 2, dt = wave & 3;
        const int r0t = tile ? r0B : r0A;
        const int cb  = tile ? sbBase : 0;
        const __hip_bfloat16* vtrow = Vt + ((size_t)(bh * 64 + dt * 16 + lr)) * 1024;

        f32x4 acc0 = (f32x4){0.f, 0.f, 0.f, 0.f};
        f32x4 acc1 = (f32x4){0.f, 0.f, 0.f, 0.f};
        for (int j0 = 0; j0 <= r0t; j0 += 64) {
            {
                const bfrag pa = *reinterpret_cast<const bfrag*>(&S[lr][cb + j0 + lk8]);
                const bfrag pb = *reinterpret_cast<const bfrag*>(&vtrow[j0 + lk8]);
                acc0 = __builtin_amdgcn_mfma_f32_16x16x32_bf16(pa, pb, acc0, 0, 0, 0);
            }
            if (j0 + 32 <= r0t) {
                const bfrag pa = *reinterpret_cast<const bfrag*>(&S[lr][cb + j0 + 32 + lk8]);
                const bfrag pb = *reinterpret_cast<const bfrag*>(&vtrow[j0 + 32 + lk8]);
                acc1 = __builtin_amdgcn_mfma_f32_16x16x32_bf16(pa, pb, acc1, 0, 0, 0);
            }
        }

#pragma unroll
        for (int j = 0; j < 4; ++j) {
            const int row = rj0 + j;
            obf[(size_t)(b * NSEQ + r0t + row) * 1024 + h * 64 + dt * 16 + lr] =
                __float2bfloat16(acc0[j] + acc1[j]);
        }
    }
}

extern "C" void kernel_launch(void* const* d_in, const int* in_sizes, int n_in,
                              void* d_out, int out_size, void* d_ws, size_t ws_size,
                              hipStream_t stream) {
    const float* x    = (const float*)d_in[0];   // [B,N,D]
    const float* Wqkv = (const float*)d_in[1];   // [3D, D]
    const float* Wo   = (const float*)d_in[2];   // [D, D]
    float* out = (float*)d_out;                  // [B,N,D] fp32

    const int M = BATCH * NSEQ;                  // 2048
    char* ws = (char*)d_ws;
    __hip_bfloat16* wqbf = (__hip_bfloat16*)ws; ws += (size_t)3 * DMODEL * DMODEL * 2;
    __hip_bfloat16* wobf = (__hip_bfloat16*)ws; ws += (size_t)DMODEL * DMODEL * 2;
    __hip_bfloat16* qkvb = (__hip_bfloat16*)ws; ws += (size_t)M * 3 * DMODEL * 2;
    __hip_bfloat16* Vt   = (__hip_bfloat16*)ws; ws += (size_t)BATCH * HNUM * DH * NSEQ * 2;
    __hip_bfloat16* obf  = (__hip_bfloat16*)ws; ws += (size_t)M * DMODEL * 2;

    dim3 blk(256);
    cast2<<<2048, blk, 0, stream>>>(Wqkv, wqbf, 3 * DMODEL * DMODEL / 4,
                                    Wo, wobf, DMODEL * DMODEL / 4);

    dim3 g1(3 * DMODEL / 128, M / 64);           // (24,32) = 768 blocks
    gemm1_qkv<<<g1, blk, 0, stream>>>(x, wqbf, qkvb, Vt, M, 3 * DMODEL, DMODEL);

    attn_mfma<<<1024, dim3(512), 0, stream>>>(qkvb, Vt, obf);

    dim3 g2(DMODEL / 64, M / 64);                // (16,32) = 512 blocks
    gemm_bt64<<<g2, blk, 0, stream>>>(obf, wobf, out, M, DMODEL, DMODEL);
}

// Round 20
// 100.203 us; speedup vs baseline: 1.1077x; 1.1077x over previous
//
#include <hip/hip_runtime.h>
#include <hip/hip_bf16.h>
#include <math.h>

#define HNUM 16
#define DH 64
#define NSEQ 1024
#define BATCH 2
#define DMODEL 1024
#define SCALE 0.125f
#define EPS 1e-6f
#define NUM_ITER 4
#define SPAD_T 1080  // u16/row: 2160B = 135 16B-slots (odd) -> frag reads 2-way max (free)

typedef float f32x4 __attribute__((ext_vector_type(4)));
typedef short bfrag __attribute__((ext_vector_type(8)));     // 8 bf16 = 4 VGPR
typedef unsigned int u32x4 __attribute__((ext_vector_type(4)));

__device__ inline float bf2f_u(unsigned int u) {
    return __builtin_bit_cast(float, u << 16);
}
__device__ inline unsigned short f2bf_u(float f) {
    return __builtin_bit_cast(unsigned short, __float2bfloat16(f));
}

// async global->LDS, 16B per lane; LDS dest must be lane-linear (it is).
__device__ inline void gload16(const __hip_bfloat16* g, __hip_bfloat16* l) {
    __builtin_amdgcn_global_load_lds(
        (const __attribute__((address_space(1))) void*)g,
        (__attribute__((address_space(3))) void*)l, 16, 0, 0);
}

// ---------------------------------------------------------------------------
// DPP wave64 reductions (R16, proven): VALU-pipe latency instead of DS-pipe.
// SUM: bound_ctrl fetch-0 (invalid lanes add +0.0, exact).
// MAX: old = own value (fmax(x,x), exact).
// ---------------------------------------------------------------------------
__device__ __forceinline__ float dpp_sum64(float x) {
    int v = __builtin_bit_cast(int, x);
    float t;
    t = __builtin_bit_cast(float, __builtin_amdgcn_update_dpp(0, v, 0x111, 0xf, 0xf, true));  x += t; v = __builtin_bit_cast(int, x);
    t = __builtin_bit_cast(float, __builtin_amdgcn_update_dpp(0, v, 0x112, 0xf, 0xf, true));  x += t; v = __builtin_bit_cast(int, x);
    t = __builtin_bit_cast(float, __builtin_amdgcn_update_dpp(0, v, 0x114, 0xf, 0xf, true));  x += t; v = __builtin_bit_cast(int, x);
    t = __builtin_bit_cast(float, __builtin_amdgcn_update_dpp(0, v, 0x118, 0xf, 0xf, true));  x += t; v = __builtin_bit_cast(int, x);
    t = __builtin_bit_cast(float, __builtin_amdgcn_update_dpp(0, v, 0x142, 0xf, 0xf, true));  x += t; v = __builtin_bit_cast(int, x);
    t = __builtin_bit_cast(float, __builtin_amdgcn_update_dpp(0, v, 0x143, 0xf, 0xf, true));  x += t; v = __builtin_bit_cast(int, x);
    return __builtin_bit_cast(float, __builtin_amdgcn_readlane(v, 63));
}
__device__ __forceinline__ float dpp_max64(float x) {
    int v = __builtin_bit_cast(int, x);
    float t;
    t = __builtin_bit_cast(float, __builtin_amdgcn_update_dpp(v, v, 0x111, 0xf, 0xf, false)); x = fmaxf(x, t); v = __builtin_bit_cast(int, x);
    t = __builtin_bit_cast(float, __builtin_amdgcn_update_dpp(v, v, 0x112, 0xf, 0xf, false)); x = fmaxf(x, t); v = __builtin_bit_cast(int, x);
    t = __builtin_bit_cast(float, __builtin_amdgcn_update_dpp(v, v, 0x114, 0xf, 0xf, false)); x = fmaxf(x, t); v = __builtin_bit_cast(int, x);
    t = __builtin_bit_cast(float, __builtin_amdgcn_update_dpp(v, v, 0x118, 0xf, 0xf, false)); x = fmaxf(x, t); v = __builtin_bit_cast(int, x);
    t = __builtin_bit_cast(float, __builtin_amdgcn_update_dpp(v, v, 0x142, 0xf, 0xf, false)); x = fmaxf(x, t); v = __builtin_bit_cast(int, x);
    t = __builtin_bit_cast(float, __builtin_amdgcn_update_dpp(v, v, 0x143, 0xf, 0xf, false)); x = fmaxf(x, t); v = __builtin_bit_cast(int, x);
    return __builtin_bit_cast(float, __builtin_amdgcn_readlane(v, 63));
}

// ---------------------------------------------------------------------------
// Fused fp32 -> bf16 cast of the three inputs, float4-vectorized.
// ---------------------------------------------------------------------------
__global__ __launch_bounds__(256) void cast3(const float* __restrict__ s0, __hip_bfloat16* __restrict__ d0, int n0,
                                             const float* __restrict__ s1, __hip_bfloat16* __restrict__ d1, int n1,
                                             const float* __restrict__ s2, __hip_bfloat16* __restrict__ d2, int n2) {
    const int stride = gridDim.x * blockDim.x;
    const int tot = n0 + n1 + n2;           // in float4 units
    for (int i = blockIdx.x * blockDim.x + threadIdx.x; i < tot; i += stride) {
        const float* s; __hip_bfloat16* d; int off;
        if (i < n0)            { s = s0; d = d0; off = i; }
        else if (i < n0 + n1)  { s = s1; d = d1; off = i - n0; }
        else                   { s = s2; d = d2; off = i - n0 - n1; }
        const float4 v = *reinterpret_cast<const float4*>(&s[(size_t)off * 4]);
        ushort4 o;
        o.x = f2bf_u(v.x); o.y = f2bf_u(v.y); o.z = f2bf_u(v.z); o.w = f2bf_u(v.w);
        *reinterpret_cast<ushort4*>(&d[(size_t)off * 4]) = o;
    }
}

// ---------------------------------------------------------------------------
// GEMM1 (QKV projection) with FUSED V-TRANSPOSE epilogue.
// C[M,3072](bf16) = A[M,K] @ B[3072,K]^T, bf16 in, global_load_lds staging,
// 64x128 tile, BK=64, 4 waves each 32x64 (2x4 frags).
// ---------------------------------------------------------------------------
__global__ __launch_bounds__(256) void gemm1_qkv(const __hip_bfloat16* __restrict__ A,
                                                 const __hip_bfloat16* __restrict__ B,
                                                 __hip_bfloat16* __restrict__ qkvb,
                                                 __hip_bfloat16* __restrict__ Vt,
                                                 int M, int Nc, int K) {
    __shared__ __align__(16) __hip_bfloat16 As[64 * 64];
    __shared__ __align__(16) __hip_bfloat16 Bs[128 * 64];
    const int tid  = threadIdx.x;
    const int l    = tid & 63;
    const int wave = tid >> 6;
    const int m0 = blockIdx.y * 64, n0 = blockIdx.x * 128;
    const int wr = (wave >> 1) * 32, wc = (wave & 1) * 64;
    const int lr = l & 15;
    const int lk = (l >> 4) * 8;

    f32x4 acc[2][4];
#pragma unroll
    for (int m = 0; m < 2; ++m)
#pragma unroll
        for (int n = 0; n < 4; ++n) acc[m][n] = (f32x4){0.f, 0.f, 0.f, 0.f};

    for (int k0 = 0; k0 < K; k0 += 64) {
#pragma unroll
        for (int p = 0; p < 2; ++p) {
            const int idx = tid + p * 256;
            const int r = idx >> 3, ce = (idx & 7) * 8;
            gload16(&A[(size_t)(m0 + r) * K + k0 + ce], &As[idx * 8]);
        }
#pragma unroll
        for (int p = 0; p < 4; ++p) {
            const int idx = tid + p * 256;
            const int r = idx >> 3, ce = (idx & 7) * 8;
            gload16(&B[(size_t)(n0 + r) * K + k0 + ce], &Bs[idx * 8]);
        }
        __syncthreads();

#pragma unroll
        for (int kk = 0; kk < 64; kk += 32) {
            bfrag af[2], bfr[4];
#pragma unroll
            for (int m = 0; m < 2; ++m)
                af[m] = *reinterpret_cast<const bfrag*>(&As[(wr + m * 16 + lr) * 64 + kk + lk]);
#pragma unroll
            for (int n = 0; n < 4; ++n)
                bfr[n] = *reinterpret_cast<const bfrag*>(&Bs[(wc + n * 16 + lr) * 64 + kk + lk]);
#pragma unroll
            for (int m = 0; m < 2; ++m)
#pragma unroll
                for (int n = 0; n < 4; ++n)
                    acc[m][n] = __builtin_amdgcn_mfma_f32_16x16x32_bf16(
                        af[m], bfr[n], acc[m][n], 0, 0, 0);
        }
        __syncthreads();
    }

#pragma unroll
    for (int m = 0; m < 2; ++m) {
        const int row0 = m0 + wr + m * 16 + (l >> 4) * 4;   // 4-aligned, same batch
#pragma unroll
        for (int n = 0; n < 4; ++n) {
            const int col = n0 + wc + n * 16 + lr;
            if (col < 2048) {                                // Q/K -> qkvb
#pragma unroll
                for (int j = 0; j < 4; ++j)
                    qkvb[(size_t)(row0 + j) * Nc + col] = __float2bfloat16(acc[m][n][j]);
            } else {                                         // V -> Vt (transposed)
                const int rc = col - 2048;
                const int bh = (row0 >> 10) * 16 + (rc >> 6);
                const int d  = rc & 63;
                ushort4 pk;
                pk.x = f2bf_u(acc[m][n][0]);
                pk.y = f2bf_u(acc[m][n][1]);
                pk.z = f2bf_u(acc[m][n][2]);
                pk.w = f2bf_u(acc[m][n][3]);
                *reinterpret_cast<ushort4*>(
                    &Vt[((size_t)(bh * 64 + d)) * 1024 + (row0 & 1023)]) = pk;
            }
        }
    }
}

// ---------------------------------------------------------------------------
// GEMM2: C[M,Nc](f32) = A[M,K](bf16) @ B[Nc,K](bf16)^T.  64x64 tile, BK=64,
// global_load_lds staging, 4 waves each 32x32 (2x2 frags).  512 blocks.
// ---------------------------------------------------------------------------
__global__ __launch_bounds__(256) void gemm_bt64(const __hip_bfloat16* __restrict__ A,
                                                 const __hip_bfloat16* __restrict__ B,
                                                 float* __restrict__ C,
                                                 int M, int Nc, int K) {
    __shared__ __align__(16) __hip_bfloat16 As[64 * 64];
    __shared__ __align__(16) __hip_bfloat16 Bs[64 * 64];
    const int tid  = threadIdx.x;
    const int l    = tid & 63;
    const int wave = tid >> 6;
    const int m0 = blockIdx.y * 64, n0 = blockIdx.x * 64;
    const int wr = (wave >> 1) * 32, wc = (wave & 1) * 32;
    const int lr = l & 15;
    const int lk = (l >> 4) * 8;

    f32x4 acc[2][2];
#pragma unroll
    for (int m = 0; m < 2; ++m)
#pragma unroll
        for (int n = 0; n < 2; ++n) acc[m][n] = (f32x4){0.f, 0.f, 0.f, 0.f};

    for (int k0 = 0; k0 < K; k0 += 64) {
#pragma unroll
        for (int p = 0; p < 2; ++p) {
            const int idx = tid + p * 256;
            const int r = idx >> 3, ce = (idx & 7) * 8;
            gload16(&A[(size_t)(m0 + r) * K + k0 + ce], &As[idx * 8]);
        }
#pragma unroll
        for (int p = 0; p < 2; ++p) {
            const int idx = tid + p * 256;
            const int r = idx >> 3, ce = (idx & 7) * 8;
            gload16(&B[(size_t)(n0 + r) * K + k0 + ce], &Bs[idx * 8]);
        }
        __syncthreads();

#pragma unroll
        for (int kk = 0; kk < 64; kk += 32) {
            bfrag af[2], bfr[2];
#pragma unroll
            for (int m = 0; m < 2; ++m)
                af[m] = *reinterpret_cast<const bfrag*>(&As[(wr + m * 16 + lr) * 64 + kk + lk]);
#pragma unroll
            for (int n = 0; n < 2; ++n)
                bfr[n] = *reinterpret_cast<const bfrag*>(&Bs[(wc + n * 16 + lr) * 64 + kk + lk]);
#pragma unroll
            for (int m = 0; m < 2; ++m)
#pragma unroll
                for (int n = 0; n < 2; ++n)
                    acc[m][n] = __builtin_amdgcn_mfma_f32_16x16x32_bf16(
                        af[m], bfr[n], acc[m][n], 0, 0, 0);
        }
        __syncthreads();
    }

#pragma unroll
    for (int m = 0; m < 2; ++m) {
        const int row0 = m0 + wr + m * 16 + (l >> 4) * 4;
#pragma unroll
        for (int n = 0; n < 2; ++n) {
            const int col = n0 + wc + n * 16 + lr;
#pragma unroll
            for (int j = 0; j < 4; ++j)
                C[(size_t)(row0 + j) * Nc + col] = acc[m][n][j];
        }
    }
}

// ---------------------------------------------------------------------------
// Dual-row Newton + fused P write-back, EXACT 128-col chunk counts,
// DPP reductions (R16, best-measured form).
// ---------------------------------------------------------------------------
template <int NCA, int NCB>
__device__ inline void newton2_wb(unsigned short* __restrict__ SA,
                                  unsigned short* __restrict__ SB,
                                  int ncolsA, int ncolsB,
                                  int limitA, int limitB, int lane) {
    float svA[NCA * 2], svB[NCB * 2];
#pragma unroll
    for (int t = 0; t < NCA; ++t) {
        const int c = lane * 2 + t * 128;
        int ca = c;
        if (t == NCA - 1) ca = (c < ncolsA) ? c : 0;   // in-region addr
        const unsigned int u = *reinterpret_cast<const unsigned int*>(&SA[ca]);
        float v0 = bf2f_u(u & 0xffffu), v1 = bf2f_u(u >> 16);
        if (t == NCA - 1) {
            v0 = (c     < ncolsA) ? v0 : -1e30f;
            v1 = (c + 1 < ncolsA) ? v1 : -1e30f;
        }
        svA[2 * t] = v0; svA[2 * t + 1] = v1;
    }
#pragma unroll
    for (int t = 0; t < NCB; ++t) {
        const int c = lane * 2 + t * 128;
        int cbm = c;
        if (t == NCB - 1) cbm = (c < ncolsB) ? c : 0;
        const unsigned int u = *reinterpret_cast<const unsigned int*>(&SB[cbm]);
        float v0 = bf2f_u(u & 0xffffu), v1 = bf2f_u(u >> 16);
        if (t == NCB - 1) {
            v0 = (c     < ncolsB) ? v0 : -1e30f;
            v1 = (c + 1 < ncolsB) ? v1 : -1e30f;
        }
        svB[2 * t] = v0; svB[2 * t + 1] = v1;
    }

    float mA = svA[0], mB = svB[0];
#pragma unroll
    for (int e = 1; e < 2 * NCA; ++e) mA = fmaxf(mA, svA[e]);
#pragma unroll
    for (int e = 1; e < 2 * NCB; ++e) mB = fmaxf(mB, svB[e]);
    mA = dpp_max64(mA);
    mB = dpp_max64(mB);
    float lamA = mA + 1.0f, lamB = mB + 1.0f;

    for (int it = 0; it < NUM_ITER; ++it) {
        float fA = 0.f, fpA = 0.f, fB = 0.f, fpB = 0.f;
#pragma unroll
        for (int e = 0; e < 2 * NCA; ++e) {
            const float iA = __builtin_amdgcn_rcpf(fmaxf(lamA - svA[e], EPS));
            fA += iA; fpA = fmaf(iA, iA, fpA);
        }
#pragma unroll
        for (int e = 0; e < 2 * NCB; ++e) {
            const float iB = __builtin_amdgcn_rcpf(fmaxf(lamB - svB[e], EPS));
            fB += iB; fpB = fmaf(iB, iB, fpB);
        }
        fA = dpp_sum64(fA);  fpA = dpp_sum64(fpA);
        fB = dpp_sum64(fB);  fpB = dpp_sum64(fpB);
        lamA += (fA - 1.0f) * __builtin_amdgcn_rcpf(fpA);
        lamB += (fB - 1.0f) * __builtin_amdgcn_rcpf(fpB);
    }

    float swA = 0.f, swB = 0.f;
#pragma unroll
    for (int e = 0; e < 2 * NCA; ++e) {
        svA[e] = __builtin_amdgcn_rcpf(fmaxf(lamA - svA[e], EPS)); swA += svA[e];
    }
#pragma unroll
    for (int e = 0; e < 2 * NCB; ++e) {
        svB[e] = __builtin_amdgcn_rcpf(fmaxf(lamB - svB[e], EPS)); swB += svB[e];
    }
    swA = dpp_sum64(swA);
    swB = dpp_sum64(swB);
    const float iswA = __builtin_amdgcn_rcpf(swA);
    const float iswB = __builtin_amdgcn_rcpf(swB);

#pragma unroll
    for (int t = 0; t < NCA; ++t) {
        const int c = lane * 2 + t * 128;
        if (t * 128 < limitA && c < limitA) {
            const unsigned int pk = (unsigned)f2bf_u(svA[2 * t] * iswA)
                                  | ((unsigned)f2bf_u(svA[2 * t + 1] * iswA) << 16);
            *reinterpret_cast<unsigned int*>(&SA[c]) = pk;
        }
    }
#pragma unroll
    for (int t = 0; t < NCB; ++t) {
        const int c = lane * 2 + t * 128;
        if (t * 128 < limitB && c < limitB) {
            const unsigned int pk = (unsigned)f2bf_u(svB[2 * t] * iswB)
                                  | ((unsigned)f2bf_u(svB[2 * t + 1] * iswB) << 16);
            *reinterpret_cast<unsigned int*>(&SB[c]) = pk;
        }
    }
}

// ---------------------------------------------------------------------------
// MFMA Stieltjes attention, PAIRED TILES + XCD swizzle + P1 prefetch + DPP
// Newton (R16 best-measured form).  1024 blocks, 512 thr / 8 waves.
// ---------------------------------------------------------------------------
__global__ __launch_bounds__(512) void attn_mfma(const __hip_bfloat16* __restrict__ qkvb,
                                                 const __hip_bfloat16* __restrict__ Vt,
                                                 __hip_bfloat16* __restrict__ obf) {
    const int tid  = threadIdx.x;
    const int lane = tid & 63;
    const int wave = tid >> 6;               // 0..7
    const int bid  = ((blockIdx.x & 7) << 7) | (blockIdx.x >> 3);   // XCD swizzle
    const int pair = bid & 31;
    const int bh   = bid >> 5;
    const int b = bh >> 4, h = bh & 15;
    const int qtA = pair, qtB = 63 - pair;
    const int r0A = qtA * 16, r0B = qtB * 16;
    const int sbBase = r0A + 32;             // 16-elem multiple -> 32B aligned

    __shared__ __align__(16) unsigned short S[16][SPAD_T];

    const size_t qbase = (size_t)(b * NSEQ) * 3072;
    const int lr  = lane & 15;
    const int lk8 = (lane >> 4) * 8;
    const int rj0 = (lane >> 4) * 4;

    // ---- Q fragments for both tiles (from global; L1/L2-hot) ----
    const __hip_bfloat16* qrowA = qkvb + qbase + (size_t)(r0A + lr) * 3072 + h * 64;
    const __hip_bfloat16* qrowB = qkvb + qbase + (size_t)(r0B + lr) * 3072 + h * 64;
    const bfrag aA0 = *reinterpret_cast<const bfrag*>(&qrowA[lk8]);
    const bfrag aA1 = *reinterpret_cast<const bfrag*>(&qrowA[32 + lk8]);
    const bfrag aB0 = *reinterpret_cast<const bfrag*>(&qrowB[lk8]);
    const bfrag aB1 = *reinterpret_cast<const bfrag*>(&qrowB[32 + lk8]);
    const __hip_bfloat16* kglob = qkvb + qbase + 1024 + h * 64;

    // ---- zero strips [r0+16, r0+32) of each tile: waves 0 and 1 ----
    if (wave < 2) {
        const int cb  = wave ? sbBase : 0;
        const int qtX = wave ? qtB : qtA;
        const int cs  = cb + (qtX + 1) * 16 + lr;
#pragma unroll
        for (int j = 0; j < 4; ++j)
            S[rj0 + j][cs] = 0;
    }

    // ---- phase 1: QK^T, 66 real tasks, wave-strided w/ depth-1 prefetch ----
    {
        const int ntA1 = qtA + 1;
        const int ntot = ntA1 + qtB + 1;
        int t = wave;
        bool isA = true; int jt = 0;
        bfrag b0{}, b1{};
        if (t < ntot) {
            isA = (t < ntA1);
            jt  = isA ? t : t - ntA1;
            const __hip_bfloat16* kp = &kglob[(size_t)(jt * 16 + lr) * 3072];
            b0 = *reinterpret_cast<const bfrag*>(&kp[lk8]);
            b1 = *reinterpret_cast<const bfrag*>(&kp[32 + lk8]);
        }
        while (t < ntot) {
            const int t2 = t + 8;
            bool isA2 = false; int jt2 = 0;
            bfrag nb0{}, nb1{};
            if (t2 < ntot) {                          // prefetch next task's K
                isA2 = (t2 < ntA1);
                jt2  = isA2 ? t2 : t2 - ntA1;
                const __hip_bfloat16* kp2 = &kglob[(size_t)(jt2 * 16 + lr) * 3072];
                nb0 = *reinterpret_cast<const bfrag*>(&kp2[lk8]);
                nb1 = *reinterpret_cast<const bfrag*>(&kp2[32 + lk8]);
            }
            f32x4 c = (f32x4){0.f, 0.f, 0.f, 0.f};
            c = __builtin_amdgcn_mfma_f32_16x16x32_bf16(isA ? aA0 : aB0, b0, c, 0, 0, 0);
            c = __builtin_amdgcn_mfma_f32_16x16x32_bf16(isA ? aA1 : aB1, b1, c, 0, 0, 0);
            const int cb = isA ? 0 : sbBase;
#pragma unroll
            for (int j = 0; j < 4; ++j)
                S[rj0 + j][cb + jt * 16 + lr] = f2bf_u(c[j] * SCALE);
            t = t2; isA = isA2; jt = jt2; b0 = nb0; b1 = nb1;
        }
    }
    __syncthreads();

    // ---- phase 2: paired-row Newton w/ fused write-back, exact chunks ----
    {
        const int limitA = r0A + 16, limitB = r0B + 16;
        for (int p = 0; p < 2; ++p) {
            const int row = wave * 2 + p;
            const int ncolsA = r0A + row + 1, ncolsB = r0B + row + 1;
            const int nca = (ncolsA + 127) >> 7;      // 1..4
            const int ncb = (ncolsB + 127) >> 7;      // 5..8
            switch ((nca - 1) * 4 + (ncb - 5)) {
                case 0:  newton2_wb<1, 5>(&S[row][0], &S[row][sbBase], ncolsA, ncolsB, limitA, limitB, lane); break;
                case 1:  newton2_wb<1, 6>(&S[row][0], &S[row][sbBase], ncolsA, ncolsB, limitA, limitB, lane); break;
                case 2:  newton2_wb<1, 7>(&S[row][0], &S[row][sbBase], ncolsA, ncolsB, limitA, limitB, lane); break;
                case 3:  newton2_wb<1, 8>(&S[row][0], &S[row][sbBase], ncolsA, ncolsB, limitA, limitB, lane); break;
                case 4:  newton2_wb<2, 5>(&S[row][0], &S[row][sbBase], ncolsA, ncolsB, limitA, limitB, lane); break;
                case 5:  newton2_wb<2, 6>(&S[row][0], &S[row][sbBase], ncolsA, ncolsB, limitA, limitB, lane); break;
                case 6:  newton2_wb<2, 7>(&S[row][0], &S[row][sbBase], ncolsA, ncolsB, limitA, limitB, lane); break;
                case 7:  newton2_wb<2, 8>(&S[row][0], &S[row][sbBase], ncolsA, ncolsB, limitA, limitB, lane); break;
                case 8:  newton2_wb<3, 5>(&S[row][0], &S[row][sbBase], ncolsA, ncolsB, limitA, limitB, lane); break;
                case 9:  newton2_wb<3, 6>(&S[row][0], &S[row][sbBase], ncolsA, ncolsB, limitA, limitB, lane); break;
                case 10: newton2_wb<3, 7>(&S[row][0], &S[row][sbBase], ncolsA, ncolsB, limitA, limitB, lane); break;
                case 11: newton2_wb<3, 8>(&S[row][0], &S[row][sbBase], ncolsA, ncolsB, limitA, limitB, lane); break;
                case 12: newton2_wb<4, 5>(&S[row][0], &S[row][sbBase], ncolsA, ncolsB, limitA, limitB, lane); break;
                case 13: newton2_wb<4, 6>(&S[row][0], &S[row][sbBase], ncolsA, ncolsB, limitA, limitB, lane); break;
                case 14: newton2_wb<4, 7>(&S[row][0], &S[row][sbBase], ncolsA, ncolsB, limitA, limitB, lane); break;
                default: newton2_wb<4, 8>(&S[row][0], &S[row][sbBase], ncolsA, ncolsB, limitA, limitB, lane); break;
            }
        }
    }
    __syncthreads();

    // ---- phase 3: O = P.V; waves 0-3 -> tile A, 4-7 -> tile B ----
    {
        const int tile = wave >> 2, dt = wave & 3;
        const int r0t = tile ? r0B : r0A;
        const int cb  = tile ? sbBase : 0;
        const __hip_bfloat16* vtrow = Vt + ((size_t)(bh * 64 + dt * 16 + lr)) * 1024;

        f32x4 acc0 = (f32x4){0.f, 0.f, 0.f, 0.f};
        f32x4 acc1 = (f32x4){0.f, 0.f, 0.f, 0.f};
        for (int j0 = 0; j0 <= r0t; j0 += 64) {
            {
                const bfrag pa = *reinterpret_cast<const bfrag*>(&S[lr][cb + j0 + lk8]);
                const bfrag pb = *reinterpret_cast<const bfrag*>(&vtrow[j0 + lk8]);
                acc0 = __builtin_amdgcn_mfma_f32_16x16x32_bf16(pa, pb, acc0, 0, 0, 0);
            }
            if (j0 + 32 <= r0t) {
                const bfrag pa = *reinterpret_cast<const bfrag*>(&S[lr][cb + j0 + 32 + lk8]);
                const bfrag pb = *reinterpret_cast<const bfrag*>(&vtrow[j0 + 32 + lk8]);
                acc1 = __builtin_amdgcn_mfma_f32_16x16x32_bf16(pa, pb, acc1, 0, 0, 0);
            }
        }

#pragma unroll
        for (int j = 0; j < 4; ++j) {
            const int row = rj0 + j;
            obf[(size_t)(b * NSEQ + r0t + row) * 1024 + h * 64 + dt * 16 + lr] =
                __float2bfloat16(acc0[j] + acc1[j]);
        }
    }
}

extern "C" void kernel_launch(void* const* d_in, const int* in_sizes, int n_in,
                              void* d_out, int out_size, void* d_ws, size_t ws_size,
                              hipStream_t stream) {
    const float* x    = (const float*)d_in[0];   // [B,N,D]
    const float* Wqkv = (const float*)d_in[1];   // [3D, D]
    const float* Wo   = (const float*)d_in[2];   // [D, D]
    float* out = (float*)d_out;                  // [B,N,D] fp32

    const int M = BATCH * NSEQ;                  // 2048
    char* ws = (char*)d_ws;
    __hip_bfloat16* xbf  = (__hip_bfloat16*)ws; ws += (size_t)M * DMODEL * 2;
    __hip_bfloat16* wqbf = (__hip_bfloat16*)ws; ws += (size_t)3 * DMODEL * DMODEL * 2;
    __hip_bfloat16* wobf = (__hip_bfloat16*)ws; ws += (size_t)DMODEL * DMODEL * 2;
    __hip_bfloat16* qkvb = (__hip_bfloat16*)ws; ws += (size_t)M * 3 * DMODEL * 2;
    __hip_bfloat16* Vt   = (__hip_bfloat16*)ws; ws += (size_t)BATCH * HNUM * DH * NSEQ * 2;
    __hip_bfloat16* obf  = (__hip_bfloat16*)ws; ws += (size_t)M * DMODEL * 2;

    dim3 blk(256);
    cast3<<<2048, blk, 0, stream>>>(x, xbf, M * DMODEL / 4,
                                    Wqkv, wqbf, 3 * DMODEL * DMODEL / 4,
                                    Wo, wobf, DMODEL * DMODEL / 4);

    dim3 g1(3 * DMODEL / 128, M / 64);           // (24,32) = 768 blocks
    gemm1_qkv<<<g1, blk, 0, stream>>>(xbf, wqbf, qkvb, Vt, M, 3 * DMODEL, DMODEL);

    attn_mfma<<<1024, dim3(512), 0, stream>>>(qkvb, Vt, obf);

    dim3 g2(DMODEL / 64, M / 64);                // (16,32) = 512 blocks
    gemm_bt64<<<g2, blk, 0, stream>>>(obf, wobf, out, M, DMODEL, DMODEL);
}